// Round 1
// 585.249 us; speedup vs baseline: 1.0515x; 1.0515x over previous
//
#include <hip/hip_runtime.h>

typedef unsigned short u16;
typedef unsigned int   u32;
typedef __bf16 bf16x8 __attribute__((ext_vector_type(8)));
typedef float  f32x4  __attribute__((ext_vector_type(4)));
typedef float  f32x2  __attribute__((ext_vector_type(2)));
typedef unsigned short u16x8 __attribute__((ext_vector_type(8)));
typedef unsigned int   u32x2 __attribute__((ext_vector_type(2)));

#define PPB 160   // pairs per block (10 m-tiles)

__device__ __forceinline__ u16 f2bf(float f){
  union { float f; u32 i; } v; v.f = f;
  u32 u = v.i;
  u += 0x7fffu + ((u >> 16) & 1u);   // RNE (finite values only)
  return (u16)(u >> 16);
}
__device__ __forceinline__ float tanh_fast(float x){
  x = fminf(fmaxf(x, -12.f), 12.f);
  float t = __builtin_amdgcn_exp2f(x * 2.885390081777926815f); // e^{2x}
  return (t - 1.f) * __builtin_amdgcn_rcpf(t + 1.f);
}

// ------- transpose+downcast: in f32[R][C] -> out bf16[C][R]; R,C mult of 64
__global__ __launch_bounds__(256) void transpose_cast_k(
    const float* __restrict__ in, u16* __restrict__ out, int R, int C)
{
  __shared__ u16 tile[64][65];
  const int tx = threadIdx.x & 63;
  const int ty = threadIdx.x >> 6;        // 0..3
  const int c0 = blockIdx.x * 64;
  const int r0 = blockIdx.y * 64;
#pragma unroll
  for (int rr = 0; rr < 16; ++rr){
    int r = ty + rr * 4;
    tile[r][tx] = f2bf(in[(size_t)(r0 + r) * C + c0 + tx]);
  }
  __syncthreads();
#pragma unroll
  for (int rr = 0; rr < 16; ++rr){
    int r = ty + rr * 4;
    out[(size_t)(c0 + r) * R + r0 + tx] = tile[tx][r];
  }
}

// ------- W2 f32[256][512] -> w2b bf16[8][512][32]: w2b[kk][n][kl] = W2[kk*32+kl][n]
__global__ __launch_bounds__(256) void w2_block_k(
    const float* __restrict__ in, u16* __restrict__ out)
{
  __shared__ float tile[32][65];
  const int kk = blockIdx.x;       // 0..7
  const int n0 = blockIdx.y * 64;  // 0..448
  const int t  = threadIdx.x;
  {
    int r  = t >> 3;               // k-row 0..31
    int c8 = t & 7;                // 8-col group
    const float* src = in + (size_t)(kk*32 + r)*512 + n0 + c8*8;
    f32x4 v0 = *(const f32x4*)src;
    f32x4 v1 = *(const f32x4*)(src + 4);
#pragma unroll
    for (int e = 0; e < 4; ++e){
      tile[r][c8*8 + e]     = v0[e];
      tile[r][c8*8 + 4 + e] = v1[e];
    }
  }
  __syncthreads();
  {
    int c = t >> 2, part = t & 3;  // c: n within tile, part: 8-k group
    u16x8 o;
#pragma unroll
    for (int e = 0; e < 8; ++e) o[e] = f2bf(tile[part*8 + e][c]);
    *(u16x8*)(out + ((size_t)kk*512 + n0 + c)*32 + part*8) = o;
  }
}

// ---------------- fused PILayer kernel, 160 pairs / 1024 threads ----------------
// 16 waves; wave w owns W2 columns n in [w*32, w*32+32) -> awf[8][2] (64 VGPR),
// so total regs fit <=128 -> 16 waves/CU (4/SIMD) instead of 8 (2/SIMD).
// LDS tiles are XOR-swizzled at 16B-chunk granularity (chunk ^= row&7), pad-free:
//   sh_h    [160][256] bf16 (81920 B), sh_inter [160][64] bf16 (20480 B).
// Phase 0: inter = bf16(p1[i]+p1[j]); Phase 1: h = bf16(tanh(inter@W1));
// Phase 2: per 16-pair tile: h @ W2 (fp32 acc), fold basis, store out.
__global__ __launch_bounds__(1024, 4) void pilayer_kernel(
    const float* __restrict__ p1,     // [N_NODES][64] f32
    const int* __restrict__ pair_i,   // [NP]
    const int* __restrict__ pair_j,   // [NP]
    const float* __restrict__ basis,  // [NP][8] f32
    const u16* __restrict__ w1t,      // [256][64] bf16
    const u16* __restrict__ w2b,      // [8][512][32] bf16 (k-blocked W2^T)
    float* __restrict__ out,          // [NP][64] f32
    int n_pairs)
{
  extern __shared__ __align__(16) u16 smem[];
  u16* sh_h     = smem;              // [160][256] swizzled = 81920 B
  u16* sh_inter = smem + PPB * 256;  // [160][64]  swizzled = 20480 B

  const int tid  = threadIdx.x;
  const int blk  = blockIdx.x;
  const int lane = tid & 63;
  const int w    = tid >> 6;     // wave 0..15
  const int m16  = lane & 15;
  const int q    = lane >> 4;    // quad 0..3
  const int sw   = m16 & 7;      // row-XOR for 16B chunks

  // ---- Persistent W2 fragment load (issued first, drains under phases 0/1) ----
  bf16x8 awf[8][2];
#pragma unroll
  for (int kk = 0; kk < 8; ++kk)
#pragma unroll
    for (int nt = 0; nt < 2; ++nt)
      awf[kk][nt] = *(const bf16x8*)(
          w2b + ((size_t)kk*512 + w*32 + nt*16 + m16)*32 + q*8);
  __builtin_amdgcn_sched_barrier(0);   // keep these loads issued up-front

  // ---- Phase 0: gather inter = bf16(p1[i] + p1[j]) into LDS (8-float units) ----
  for (int u = tid; u < PPB * 8; u += 1024){
    int m   = u >> 3;            // pair row 0..159
    int seg = u & 7;             // 8 floats per segment = one 16B bf16 chunk
    int p   = blk * PPB + m;
    if (p >= n_pairs) p = n_pairs - 1;
    const f32x4* pi = (const f32x4*)(p1 + (size_t)pair_i[p] * 64 + seg * 8);
    const f32x4* pj = (const f32x4*)(p1 + (size_t)pair_j[p] * 64 + seg * 8);
    f32x4 a0 = pi[0], a1 = pi[1];
    f32x4 c0 = pj[0], c1 = pj[1];
    u16x8 r;
#pragma unroll
    for (int e = 0; e < 4; ++e){
      r[e]     = f2bf(a0[e] + c0[e]);
      r[e + 4] = f2bf(a1[e] + c1[e]);
    }
    *(u16x8*)(sh_inter + m * 64 + ((seg ^ (m & 7)) * 8)) = r;
  }
  __syncthreads();

  // ---- Phase 1: h = bf16(tanh(inter @ W1)) -> sh_h ----
  // Wave w computes n-rows [w*16, w*16+16) for all 160 pairs.
  {
    const u16* arow = w1t + (size_t)(w*16 + m16)*64 + q*8;
    bf16x8 af0 = *(const bf16x8*)(arow);
    bf16x8 af1 = *(const bf16x8*)(arow + 32);
    const int cw = (w*2 + (q >> 1)) ^ sw;   // swizzled 16B chunk for the write
    for (int mt1 = 0; mt1 < PPB/16; ++mt1){
      const u16* irow = sh_inter + (size_t)(mt1*16 + m16) * 64;
      bf16x8 b0 = *(const bf16x8*)(irow + (q ^ sw) * 8);
      bf16x8 b1 = *(const bf16x8*)(irow + ((q + 4) ^ sw) * 8);
      f32x4 acc = {0.f, 0.f, 0.f, 0.f};
      acc = __builtin_amdgcn_mfma_f32_16x16x32_bf16(af0, b0, acc, 0, 0, 0);
      acc = __builtin_amdgcn_mfma_f32_16x16x32_bf16(af1, b1, acc, 0, 0, 0);
      u32 lo = (u32)f2bf(tanh_fast(acc[0])) | ((u32)f2bf(tanh_fast(acc[1])) << 16);
      u32 hi = (u32)f2bf(tanh_fast(acc[2])) | ((u32)f2bf(tanh_fast(acc[3])) << 16);
      u32x2 pk = {lo, hi};
      *(u32x2*)(sh_h + (size_t)(mt1*16 + m16)*256 + cw*8 + (q & 1)*4) = pk;
    }
  }
  __syncthreads();

  // ---- Phase 2: per m-tile GEMM2 against register-resident W2, fold basis ----
  for (int mt = 0; mt < PPB/16; ++mt){
    const int row = mt*16 + m16;
    const int mg  = blk * PPB + row;
    const int mgc = (mg < n_pairs) ? mg : (n_pairs - 1);
    f32x4 bb = *(const f32x4*)(basis + (size_t)mgc*8 + (q & 1)*4);

    const u16* hbase = sh_h + (size_t)row * 256;
    f32x4 acc0 = {0.f, 0.f, 0.f, 0.f};
    f32x4 acc1 = {0.f, 0.f, 0.f, 0.f};

    bf16x8 bh = *(const bf16x8*)(hbase + (q ^ sw) * 8);     // chunk kk=0 -> q
#pragma unroll
    for (int kk = 0; kk < 8; ++kk){
      bf16x8 bhn;
      if (kk < 7) bhn = *(const bf16x8*)(hbase + ((((kk + 1)*4 + q) ^ sw) * 8));
      acc0 = __builtin_amdgcn_mfma_f32_16x16x32_bf16(awf[kk][0], bh, acc0, 0, 0, 0);
      acc1 = __builtin_amdgcn_mfma_f32_16x16x32_bf16(awf[kk][1], bh, acc1, 0, 0, 0);
      bh = bhn;
    }

    // n = w*32 + nt*16 + q*4 + reg; c = w*4 + nt*2 + (q>>1); b = (q&1)*4 + reg
#pragma unroll
    for (int nt = 0; nt < 2; ++nt){
      f32x4 a = (nt == 0) ? acc0 : acc1;
      float s = a[0]*bb[0] + a[1]*bb[1] + a[2]*bb[2] + a[3]*bb[3];
      s += __shfl_xor(s, 16);          // sum b-halves (q0+q1 / q2+q3)
      float v2 = __shfl_xor(s, 32);    // partner c-channel
      if (q == 0 && mg < n_pairs){
        f32x2 pk = {s, v2};
        *(f32x2*)(out + (size_t)mg*64 + w*4 + nt*2) = pk;
      }
    }
  }
}

extern "C" void kernel_launch(void* const* d_in, const int* in_sizes, int n_in,
                              void* d_out, int out_size, void* d_ws, size_t ws_size,
                              hipStream_t stream)
{
  const float* p1    = (const float*)d_in[0];
  const int*   pi    = (const int*)d_in[1];
  const int*   pj    = (const int*)d_in[2];
  const float* basis = (const float*)d_in[3];
  const float* W1    = (const float*)d_in[4];  // [64][256] f32
  const float* W2    = (const float*)d_in[5];  // [256][512] f32
  float* out = (float*)d_out;

  u16* w1t = (u16*)d_ws;                   // [256][64]   bf16 = 32 KB
  u16* w2b = w1t + 64 * 256;               // [8][512][32] bf16 = 256 KB

  const int n_pairs = in_sizes[1];
  const int lds_bytes = (PPB * 256 + PPB * 64) * (int)sizeof(u16);  // 102400

  static int attr_done = 0;  // attribute is device-global state, not stream work;
  if (!attr_done){           // first (uncaptured) call sets it before capture
    hipFuncSetAttribute((const void*)pilayer_kernel,
                        hipFuncAttributeMaxDynamicSharedMemorySize, lds_bytes);
    attr_done = 1;
  }

  transpose_cast_k<<<dim3(4, 1), 256, 0, stream>>>(W1, w1t, 64, 256);
  w2_block_k<<<dim3(8, 8), 256, 0, stream>>>(W2, w2b);

  const int blocks = (n_pairs + PPB - 1) / PPB;
  pilayer_kernel<<<blocks, 1024, lds_bytes, stream>>>(
      p1, pi, pj, basis, w1t, w2b, out, n_pairs);
}